// Round 9
// baseline (298.237 us; speedup 1.0000x reference)
//
#include <hip/hip_runtime.h>
#include <math.h>

#define N_PTS   1000000
#define CI      10
#define C       64
#define NSEG    30000
#define BN_EPS  1e-3f
#define FROFF   31104      // float index of fragment blob (after starts ints)

// ws layout (floats):
// moments: scalar k at ws[7*k], k<65   (stride-7 floats spreads atomic fan-in)
// g_sum:   channel c at ws[512 + 8*c]
// int slot 961: block-done counter for k_gstats last-block prep (memset-zeroed)
// ints at [1024:31024): segment starts
// [FROFF : FROFF+15*256): per-lane fragment blob, 15 items x 64 lanes x 16B
#define MSTR 7
#define GOFF 512
#define GSTR 8
#define CTRI 961

using f32x4 = __attribute__((ext_vector_type(4))) float;
using s16x8 = __attribute__((ext_vector_type(8))) short;

__device__ inline short f2bf(float x) {           // RNE fp32 -> bf16 (weights)
    unsigned u = __float_as_uint(x);
    unsigned r = (u + 0x7fffu + ((u >> 16) & 1u)) >> 16;
    return (short)r;
}
__device__ inline unsigned pack_trunc(float lo, float hi) {  // 2x bf16 truncate
    return (__float_as_uint(hi) & 0xffff0000u) | (__float_as_uint(lo) >> 16);
}
__device__ inline float frcp(float x) { return __builtin_amdgcn_rcpf(x); }
// LDS-only drain: write->read visibility within a wave, does NOT drain vmcnt
__device__ inline void lds_fence() {
    asm volatile("s_waitcnt lgkmcnt(0)" ::: "memory");
}

struct Rows { float2 r0, r1, r2, r3; };

// Kernel 1: colsum[10] + second-moment M[55] of raw inputs. Fused: segment
// starts. 1-deep software prefetch of rows+idx; line-spread atomics.
__global__ void __launch_bounds__(256) k_moments(const float* __restrict__ inp,
                                                 const int* __restrict__ idx,
                                                 float* __restrict__ ws,
                                                 int* __restrict__ starts) {
    const int tid = threadIdx.x;
    const int stride = gridDim.x * blockDim.x;
    float v[65];
#pragma unroll
    for (int k = 0; k < 65; ++k) v[k] = 0.f;

    int p = blockIdx.x * blockDim.x + tid;
    float2 a0, a1, a2, a3, a4;
    int ic = 0, ip = 0;
    auto ld = [&](int qq) {
        const float2* r2 = (const float2*)(inp + (size_t)qq * CI);
        a0 = r2[0]; a1 = r2[1]; a2 = r2[2]; a3 = r2[3]; a4 = r2[4];
        ic = idx[qq]; ip = (qq > 0) ? idx[qq - 1] : ic;
    };
    if (p < N_PTS) ld(p);
    while (p < N_PTS) {
        float r[CI] = {a0.x, a0.y, a1.x, a1.y, a2.x, a2.y, a3.x, a3.y, a4.x, a4.y};
        const int cc = ic, cp = ip, cq = p;
        const int pn = p + stride;
        if (pn < N_PTS) ld(pn);                       // prefetch next point

#pragma unroll
        for (int i = 0; i < CI; ++i) v[i] += r[i];
        int kk = 10;
#pragma unroll
        for (int i = 0; i < CI; ++i)
#pragma unroll
            for (int j = i; j < CI; ++j) { v[kk] = fmaf(r[i], r[j], v[kk]); ++kk; }

        if (cq == 0) starts[0] = 0;
        else if (cp != cc) starts[cc] = cq;
        p = pn;
    }

#pragma unroll
    for (int k = 0; k < 65; ++k) {
#pragma unroll
        for (int off = 32; off >= 1; off >>= 1)
            v[k] += __shfl_xor(v[k], off, 64);
    }
    __shared__ float red[4 * 65];
    const int wv = tid >> 6, ln = tid & 63;
    if (ln == 0) {
#pragma unroll
        for (int k = 0; k < 65; ++k) red[wv * 65 + k] = v[k];
    }
    __syncthreads();
    if (tid < 65)
        atomicAdd(&ws[MSTR * tid],
                  red[tid] + red[65 + tid] + red[130 + tid] + red[195 + tid]);
}

// ---------------------------------------------------------------------------
// Kernel 2: k_gstats v2 — RESTRUCTURED. Old form (4096 waves x 15 iters of
// exec-masked 8B gathers + MFMA) measured 151.8 us at 8% VALUBusy: pure
// latency exposure, never amortized. New form = the pattern k_moments proves
// fast: 2000 blocks x 500 contiguous points, coalesced float4 stage into LDS
// (block base 20000 B -> 16B aligned; 2000*500 == 1M exactly, no tail), then
// lane==channel VALU compute: 10 reg-held BN-folded weights, broadcast
// ds_read_b64 row reads, 10 FMA + relu per point, 2-pt unroll for ILP.
// Exact fp32 (closer to reference than the old bf16-MFMA path).
// Last block (atomic counter, device fence) runs the former k_prep inline.
// ---------------------------------------------------------------------------
#define GS_TP 500
__global__ void __launch_bounds__(256) k_gstats(const float* __restrict__ inp,
                                                const float* __restrict__ W,
                                                const float* __restrict__ gamma,
                                                const float* __restrict__ beta,
                                                const float* __restrict__ dw1,
                                                const float* __restrict__ pw1,
                                                const float* __restrict__ dw2,
                                                const float* __restrict__ pw2,
                                                float* __restrict__ ws) {
    const int tid  = threadIdx.x;
    const int wv   = tid >> 6;
    const int lane = tid & 63;
    const int m = lane & 15;
    const int q = lane >> 4;
    const float inv_n = 1.f / (float)N_PTS;

    __shared__ float tile[GS_TP * CI];   // 20000 B point tile
    __shared__ float wp[C * CI];         // W' = a*W (for last-block prep)
    __shared__ float bsh[C];
    __shared__ float red[4 * 64];

    // ---- stage 500 rows, coalesced float4 (1250 per block)
    {
        const float4* src = (const float4*)(inp + (size_t)blockIdx.x * GS_TP * CI);
        float4* dst = (float4*)tile;
        for (int i = tid; i < GS_TP * CI / 4; i += 256) dst[i] = src[i];
    }

    // ---- per-lane BN finalize for channel c == lane (redundant across waves)
    float wa[CI], b;
    {
        float w[CI];
#pragma unroll
        for (int i = 0; i < CI; ++i) w[i] = W[lane * CI + i];
        float mu = 0.f;
#pragma unroll
        for (int i = 0; i < CI; ++i) mu = fmaf(w[i], ws[MSTR * i], mu);
        mu *= inv_n;
        float ex2 = 0.f;
        int kk = 10;
#pragma unroll
        for (int i = 0; i < CI; ++i)
#pragma unroll
            for (int j = i; j < CI; ++j) {
                float mm = ws[MSTR * kk];
                float t = w[i] * w[j] * mm;
                ex2 += (i == j) ? t : 2.f * t;
                ++kk;
            }
        ex2 *= inv_n;
        float var = ex2 - mu * mu;
        float rstd = rsqrtf(var + BN_EPS);
        float a = rstd * gamma[lane];
        b = beta[lane] - mu * a;
#pragma unroll
        for (int i = 0; i < CI; ++i) wa[i] = a * w[i];
        if (wv == 0) {
            bsh[lane] = b;
#pragma unroll
            for (int i = 0; i < CI; ++i) wp[lane * CI + i] = wa[i];
        }
    }
    __syncthreads();   // tile staged + wp/bsh visible

    // ---- g partial: lane accumulates relu(x'_pc) over its wave's 125 points
    float g0 = 0.f, g1 = 0.f;
    const int ps = wv * 125;
    for (int p = ps; p < ps + 124; p += 2) {
        const float* r0 = &tile[p * CI];
        const float* r1 = &tile[(p + 1) * CI];
        float acc0 = b, acc1 = b;
#pragma unroll
        for (int i2 = 0; i2 < 5; ++i2) {
            float2 u0 = *(const float2*)(r0 + 2 * i2);
            float2 u1 = *(const float2*)(r1 + 2 * i2);
            acc0 = fmaf(wa[2 * i2], u0.x, fmaf(wa[2 * i2 + 1], u0.y, acc0));
            acc1 = fmaf(wa[2 * i2], u1.x, fmaf(wa[2 * i2 + 1], u1.y, acc1));
        }
        g0 += fmaxf(acc0, 0.f);
        g1 += fmaxf(acc1, 0.f);
    }
    {   // last point (125 is odd)
        const float* r0 = &tile[(ps + 124) * CI];
        float acc0 = b;
#pragma unroll
        for (int i2 = 0; i2 < 5; ++i2) {
            float2 u0 = *(const float2*)(r0 + 2 * i2);
            acc0 = fmaf(wa[2 * i2], u0.x, fmaf(wa[2 * i2 + 1], u0.y, acc0));
        }
        g0 += fmaxf(acc0, 0.f);
    }

    red[wv * 64 + lane] = g0 + g1;
    __syncthreads();
    if (tid < 64)
        atomicAdd(&ws[GOFF + GSTR * tid],
                  red[tid] + red[64 + tid] + red[128 + tid] + red[192 + tid]);

    // ---------------- last-block-done: inline prep ----------------
    __shared__ int lastf;
    __syncthreads();
    if (tid == 0) {
        __threadfence();
        int old = atomicAdd((int*)ws + CTRI, 1);
        lastf = (old == (int)gridDim.x - 1);
    }
    __syncthreads();
    if (!lastf) return;
    __threadfence();   // acquire: all blocks' g_sum adds visible

    __shared__ float T[C], XG[C];
    if (tid < 64)
        T[tid] = fmaxf(dw2[tid] * (ws[GOFF + GSTR * tid] * inv_n), 0.f);
    __syncthreads();
    if (tid < 64) {
        float acc = 0.f;
#pragma unroll
        for (int k = 0; k < C; ++k) acc = fmaf(pw2[tid * C + k], T[k], acc);
        XG[tid] = acc;
    }
    __syncthreads();

    if (tid < 64) {
        float4* FR = (float4*)(ws + FROFF);
        union { float4 f; s16x8 v; } u;

#pragma unroll
        for (int nt = 0; nt < 4; ++nt) {
            s16x8 tt;
#pragma unroll
            for (int j = 0; j < 8; ++j) {
                int k = 8 * q + j;
                tt[j] = (k < CI) ? f2bf(wp[(nt * 16 + m) * CI + k]) : (short)0;
            }
            u.v = tt; FR[nt * 64 + lane] = u.f;
        }
#pragma unroll
        for (int nt = 0; nt < 4; ++nt)
#pragma unroll
            for (int kc = 0; kc < 2; ++kc) {
                const float* src = pw1 + (nt * 16 + m) * C + kc * 32 + q * 8;
                float4 p0 = *(const float4*)src, p1 = *(const float4*)(src + 4);
                s16x8 tt;
                tt[0] = f2bf(p0.x); tt[1] = f2bf(p0.y); tt[2] = f2bf(p0.z); tt[3] = f2bf(p0.w);
                tt[4] = f2bf(p1.x); tt[5] = f2bf(p1.y); tt[6] = f2bf(p1.z); tt[7] = f2bf(p1.w);
                u.v = tt; FR[(4 + nt * 2 + kc) * 64 + lane] = u.f;
            }
        float4 f;
        f.x = bsh[m]; f.y = bsh[16 + m]; f.z = bsh[32 + m]; f.w = bsh[48 + m];
        FR[12 * 64 + lane] = f;
        f.x = dw1[m]; f.y = dw1[16 + m]; f.z = dw1[32 + m]; f.w = dw1[48 + m];
        FR[13 * 64 + lane] = f;
        f.x = XG[m]; f.y = XG[16 + m]; f.z = XG[32 + m]; f.w = XG[48 + m];
        FR[14 * 64 + lane] = f;
    }
}

// ---------------------------------------------------------------------------
// Kernel 3: k_main — EXACT round-0 structure (measured 91.6 us, the best of
// v1/v3/v4). One wave per 2 contiguous segments, 16-pt batches, single LDS
// tile + 2 lgkm fences/batch, 2-deep row prefetch, 7500 blocks x 128.
// ---------------------------------------------------------------------------
#define LD 68
#define SEGW 2
__global__ void __launch_bounds__(128) k_main(const float* __restrict__ inp,
                                              const float* __restrict__ ws,
                                              const int* __restrict__ starts,
                                              float* __restrict__ out) {
    const int tid  = threadIdx.x;
    const int wv   = tid >> 6;
    const int lane = tid & 63;
    const int m = lane & 15;
    const int q = lane >> 4;
    const f32x4 zero = {0.f, 0.f, 0.f, 0.f};

    const float4* FR = (const float4*)(ws + FROFF);
    union { float4 f; s16x8 v; } u;
    s16x8 wfr[4];
#pragma unroll
    for (int nt = 0; nt < 4; ++nt) { u.f = FR[nt * 64 + lane]; wfr[nt] = u.v; }
    s16x8 bfr[4][2];
#pragma unroll
    for (int nt = 0; nt < 4; ++nt)
#pragma unroll
        for (int kc = 0; kc < 2; ++kc) { u.f = FR[(4 + nt * 2 + kc) * 64 + lane]; bfr[nt][kc] = u.v; }
    const float4 bb4  = FR[12 * 64 + lane];
    const float4 d14  = FR[13 * 64 + lane];
    const float4 xg4  = FR[14 * 64 + lane];
    const float bb[4]  = {bb4.x, bb4.y, bb4.z, bb4.w};
    const float d1v[4] = {d14.x, d14.y, d14.z, d14.w};
    const float xgv[4] = {xg4.x, xg4.y, xg4.z, xg4.w};

    __shared__ float sb[2][16 * LD];
    float* my = sb[wv];

    const int w  = blockIdx.x * 2 + wv;    // 0..14999
    const int s0 = w * SEGW;

    int st1 = starts[s0 + 1];
    int st2 = (s0 + 2 < NSEG) ? starts[s0 + 2] : N_PTS;
    const int start   = starts[s0];
    const int end_all = st2;

    int cur = s0;
    int end_cur = st1;

    float sm[4]  = {0.f, 0.f, 0.f, 0.f};
    float mxv[4] = {-INFINITY, -INFINITY, -INFINITY, -INFINITY};

    auto flushseg = [&](int s) {
#pragma unroll
        for (int nt = 0; nt < 4; ++nt) {
            sm[nt] += __shfl_xor(sm[nt], 16, 64);
            sm[nt] += __shfl_xor(sm[nt], 32, 64);
            mxv[nt] = fmaxf(mxv[nt], __shfl_xor(mxv[nt], 16, 64));
            mxv[nt] = fmaxf(mxv[nt], __shfl_xor(mxv[nt], 32, 64));
        }
        float S = sm[0], M = mxv[0];
        if (q == 1) { S = sm[1]; M = mxv[1]; }
        if (q == 2) { S = sm[2]; M = mxv[2]; }
        if (q == 3) { S = sm[3]; M = mxv[3]; }
        out[(size_t)s * C + lane] = S + M;
#pragma unroll
        for (int nt = 0; nt < 4; ++nt) { sm[nt] = 0.f; mxv[nt] = -INFINITY; }
    };

    auto loadrows = [&](int pb) -> Rows {
        Rows R;
        R.r0 = R.r1 = R.r2 = R.r3 = make_float2(0.f, 0.f);
        const float* row = inp + (size_t)min(pb + m, N_PTS - 1) * CI;
        if (q == 0) {
            R.r0 = *(const float2*)(row);     R.r1 = *(const float2*)(row + 2);
            R.r2 = *(const float2*)(row + 4); R.r3 = *(const float2*)(row + 6);
        } else if (q == 1) {
            R.r0 = *(const float2*)(row + 8);
        }
        return R;
    };

    Rows A = loadrows(start);
    Rows B = (start + 16 < end_all) ? loadrows(start + 16) : A;

    for (int base = start; base < end_all; base += 16) {
        Rows L = A;
        A = B;
        if (base + 32 < end_all) B = loadrows(base + 32);

        const int nb = min(16, end_all - base);

        // ---- A-frag of rows (K padded to 32, truncation pack)
        union { s16x8 v; unsigned uu[4]; } t;
        t.v = s16x8{0, 0, 0, 0, 0, 0, 0, 0};
        if (q < 2) t.uu[0] = pack_trunc(L.r0.x, L.r0.y);
        if (q == 0) {
            t.uu[1] = pack_trunc(L.r1.x, L.r1.y);
            t.uu[2] = pack_trunc(L.r2.x, L.r2.y);
            t.uu[3] = pack_trunc(L.r3.x, L.r3.y);
        }

        // ---- x' = rows @ W'^T  (C-layout: ch=16nt+m, pt=4q+r)
        f32x4 xt[4];
#pragma unroll
        for (int nt = 0; nt < 4; ++nt)
            xt[nt] = __builtin_amdgcn_mfma_f32_16x16x32_bf16(t.v, wfr[nt], zero, 0, 0, 0);

        // ---- BN + ReLU + swish; sw -> LDS tile [pt][ch]
        float xn[4][4];
#pragma unroll
        for (int nt = 0; nt < 4; ++nt)
#pragma unroll
            for (int r = 0; r < 4; ++r) {
                float x = fmaxf(xt[nt][r] + bb[nt], 0.f);
                xn[nt][r] = x;
                float sg = x * d1v[nt];
                float sw = sg * frcp(1.f + __expf(-sg));
                my[(4 * q + r) * LD + nt * 16 + m] = sw;
            }
        lds_fence();

        // ---- A-frags of sw: lane(m,q) reads sw[pt=m][32kc+8q+j]
        s16x8 av[2];
#pragma unroll
        for (int kc = 0; kc < 2; ++kc) {
            const float* src = &my[m * LD + kc * 32 + q * 8];
            float4 p0 = *(const float4*)src;
            float4 p1 = *(const float4*)(src + 4);
            union { s16x8 v; unsigned uu[4]; } tt;
            tt.uu[0] = pack_trunc(p0.x, p0.y);
            tt.uu[1] = pack_trunc(p0.z, p0.w);
            tt.uu[2] = pack_trunc(p1.x, p1.y);
            tt.uu[3] = pack_trunc(p1.z, p1.w);
            av[kc] = tt.v;
        }

        // ---- xl = sw @ pw1^T (C-layout, aligned with xn)
        f32x4 xi[4];
#pragma unroll
        for (int nt = 0; nt < 4; ++nt) {
            xi[nt] = __builtin_amdgcn_mfma_f32_16x16x32_bf16(av[0], bfr[nt][0], zero, 0, 0, 0);
            xi[nt] = __builtin_amdgcn_mfma_f32_16x16x32_bf16(av[1], bfr[nt][1], xi[nt], 0, 0, 0);
        }
        lds_fence();   // reads drained before next batch overwrites the tile

#pragma unroll
        for (int nt = 0; nt < 4; ++nt)
#pragma unroll
            for (int r = 0; r < 4; ++r) {
                float v   = xi[nt][r] + xgv[nt];
                float wei = frcp(1.f + __expf(-v));
                float x   = xn[nt][r];
                xi[nt][r] = fmaf(x, wei, x);
            }

        // ---- segmented accumulate (<=1 boundary per batch: min seg len 33)
        const int fin = base + nb;
        if (fin <= end_cur) {
            if (nb == 16) {
#pragma unroll
                for (int nt = 0; nt < 4; ++nt)
#pragma unroll
                    for (int r = 0; r < 4; ++r) {
                        sm[nt] += xi[nt][r];
                        mxv[nt] = fmaxf(mxv[nt], xi[nt][r]);
                    }
            } else {
#pragma unroll
                for (int nt = 0; nt < 4; ++nt)
#pragma unroll
                    for (int r = 0; r < 4; ++r) {
                        bool act = (4 * q + r) < nb;
                        sm[nt] += act ? xi[nt][r] : 0.f;
                        mxv[nt] = fmaxf(mxv[nt], act ? xi[nt][r] : -INFINITY);
                    }
            }
            if (fin == end_cur) { flushseg(cur); ++cur; end_cur = st2; }
        } else {
            const int B = end_cur - base;   // 1..nb-1
#pragma unroll
            for (int nt = 0; nt < 4; ++nt)
#pragma unroll
                for (int r = 0; r < 4; ++r) {
                    bool act = (4 * q + r) < B;
                    sm[nt] += act ? xi[nt][r] : 0.f;
                    mxv[nt] = fmaxf(mxv[nt], act ? xi[nt][r] : -INFINITY);
                }
            flushseg(cur); ++cur;
#pragma unroll
            for (int nt = 0; nt < 4; ++nt)
#pragma unroll
                for (int r = 0; r < 4; ++r) {
                    int pt = 4 * q + r;
                    bool act = (pt >= B) && (pt < nb);
                    sm[nt] += act ? xi[nt][r] : 0.f;
                    mxv[nt] = fmaxf(mxv[nt], act ? xi[nt][r] : -INFINITY);
                }
            end_cur = st2;
        }
    }
}

extern "C" void kernel_launch(void* const* d_in, const int* in_sizes, int n_in,
                              void* d_out, int out_size, void* d_ws, size_t ws_size,
                              hipStream_t stream) {
    const float* inp   = (const float*)d_in[0];
    const int*   unq   = (const int*)d_in[1];
    const float* W     = (const float*)d_in[2];
    const float* gamma = (const float*)d_in[3];
    const float* beta  = (const float*)d_in[4];
    const float* dw1   = (const float*)d_in[5];
    const float* pw1   = (const float*)d_in[6];
    const float* dw2   = (const float*)d_in[7];
    const float* pw2   = (const float*)d_in[8];
    float* out = (float*)d_out;
    float* ws  = (float*)d_ws;
    int* starts = (int*)ws + 1024;

    hipMemsetAsync(ws, 0, 1024 * sizeof(float), stream);   // zero accumulators+ctr

    k_moments <<<1024, 256, 0, stream>>>(inp, unq, ws, starts);
    k_gstats  <<<2000, 256, 0, stream>>>(inp, W, gamma, beta, dw1, pw1, dw2, pw2, ws);
    k_main    <<<7500, 128, 0, stream>>>(inp, ws, starts, out);
}

// Round 15
// 295.987 us; speedup vs baseline: 1.0076x; 1.0076x over previous
//
#include <hip/hip_runtime.h>
#include <math.h>

#define N_PTS   1000000
#define CI      10
#define C       64
#define NSEG    30000
#define BN_EPS  1e-3f
#define FROFF   31104      // float index of fragment blob (after starts ints)

// ws layout (floats):
// moments: scalar k at ws[7*k], k<65   (stride-7 floats spreads atomic fan-in)
// g_sum:   channel c at ws[512 + 8*c]
// int slot 961: block-done counter for k_gstats last-block prep (memset-zeroed)
// ints at [1024:31024): segment starts
// [FROFF : FROFF+15*256): per-lane fragment blob, 15 items x 64 lanes x 16B
#define MSTR 7
#define GOFF 512
#define GSTR 8
#define CTRI 961

using f32x4 = __attribute__((ext_vector_type(4))) float;
using s16x8 = __attribute__((ext_vector_type(8))) short;

__device__ inline short f2bf(float x) {           // RNE fp32 -> bf16 (weights)
    unsigned u = __float_as_uint(x);
    unsigned r = (u + 0x7fffu + ((u >> 16) & 1u)) >> 16;
    return (short)r;
}
__device__ inline unsigned pack_trunc(float lo, float hi) {  // 2x bf16 truncate
    return (__float_as_uint(hi) & 0xffff0000u) | (__float_as_uint(lo) >> 16);
}
__device__ inline float frcp(float x) { return __builtin_amdgcn_rcpf(x); }
// LDS-only drain: write->read visibility within a wave, does NOT drain vmcnt
__device__ inline void lds_fence() {
    asm volatile("s_waitcnt lgkmcnt(0)" ::: "memory");
}

struct Rows { float2 r0, r1, r2, r3; };

// Kernel 1: colsum[10] + second-moment M[55] of raw inputs. Fused: segment
// starts. 1-deep software prefetch of rows+idx; line-spread atomics.
__global__ void __launch_bounds__(256) k_moments(const float* __restrict__ inp,
                                                 const int* __restrict__ idx,
                                                 float* __restrict__ ws,
                                                 int* __restrict__ starts) {
    const int tid = threadIdx.x;
    const int stride = gridDim.x * blockDim.x;
    float v[65];
#pragma unroll
    for (int k = 0; k < 65; ++k) v[k] = 0.f;

    int p = blockIdx.x * blockDim.x + tid;
    float2 a0, a1, a2, a3, a4;
    int ic = 0, ip = 0;
    auto ld = [&](int qq) {
        const float2* r2 = (const float2*)(inp + (size_t)qq * CI);
        a0 = r2[0]; a1 = r2[1]; a2 = r2[2]; a3 = r2[3]; a4 = r2[4];
        ic = idx[qq]; ip = (qq > 0) ? idx[qq - 1] : ic;
    };
    if (p < N_PTS) ld(p);
    while (p < N_PTS) {
        float r[CI] = {a0.x, a0.y, a1.x, a1.y, a2.x, a2.y, a3.x, a3.y, a4.x, a4.y};
        const int cc = ic, cp = ip, cq = p;
        const int pn = p + stride;
        if (pn < N_PTS) ld(pn);                       // prefetch next point

#pragma unroll
        for (int i = 0; i < CI; ++i) v[i] += r[i];
        int kk = 10;
#pragma unroll
        for (int i = 0; i < CI; ++i)
#pragma unroll
            for (int j = i; j < CI; ++j) { v[kk] = fmaf(r[i], r[j], v[kk]); ++kk; }

        if (cq == 0) starts[0] = 0;
        else if (cp != cc) starts[cc] = cq;
        p = pn;
    }

#pragma unroll
    for (int k = 0; k < 65; ++k) {
#pragma unroll
        for (int off = 32; off >= 1; off >>= 1)
            v[k] += __shfl_xor(v[k], off, 64);
    }
    __shared__ float red[4 * 65];
    const int wv = tid >> 6, ln = tid & 63;
    if (ln == 0) {
#pragma unroll
        for (int k = 0; k < 65; ++k) red[wv * 65 + k] = v[k];
    }
    __syncthreads();
    if (tid < 65)
        atomicAdd(&ws[MSTR * tid],
                  red[tid] + red[65 + tid] + red[130 + tid] + red[195 + tid]);
}

// ---------------------------------------------------------------------------
// Kernel 2: k_gstats v3 — ILP fix. v2 measured 92.4 us @ 24% VALUBusy:
// latency-bound on ONE 5-deep fmaf chain x2 + 5 ds_read_b64 per point.
// v3: rows padded to 48B in LDS (16B-aligned -> ds_read_b128 x2 + b64 = 3
// LDS ops/point, broadcast, conflict-free) and 4-pt unroll with even/odd
// split = 8 independent FMA chains + 4 independent g accumulators.
// Last block (atomic counter, device fence) runs the former k_prep inline.
// ---------------------------------------------------------------------------
#define GS_TP  500
#define GS_LDR 12            // padded row stride in floats (48 B)
__global__ void __launch_bounds__(256) k_gstats(const float* __restrict__ inp,
                                                const float* __restrict__ W,
                                                const float* __restrict__ gamma,
                                                const float* __restrict__ beta,
                                                const float* __restrict__ dw1,
                                                const float* __restrict__ pw1,
                                                const float* __restrict__ dw2,
                                                const float* __restrict__ pw2,
                                                float* __restrict__ ws) {
    const int tid  = threadIdx.x;
    const int wv   = tid >> 6;
    const int lane = tid & 63;
    const int m = lane & 15;
    const int q = lane >> 4;
    const float inv_n = 1.f / (float)N_PTS;

    __shared__ float tile[GS_TP * GS_LDR];   // 24000 B padded point tile
    __shared__ float wp[C * CI];             // W' = a*W (for last-block prep)
    __shared__ float bsh[C];
    __shared__ float red[4 * 64];

    // ---- stage 500 rows, coalesced float2, scatter to 48B-padded rows
    {
        const float2* src = (const float2*)(inp + (size_t)blockIdx.x * GS_TP * CI);
#pragma unroll
        for (int k = 0; k < 10; ++k) {
            int s = tid + k * 256;            // 0..2559, need < 2500
            if (s < GS_TP * CI / 2) {
                int rp = s / 5;               // row (magic-mul)
                int e  = s - rp * 5;          // float2 index within row
                *(float2*)&tile[rp * GS_LDR + 2 * e] = src[s];
            }
        }
    }

    // ---- per-lane BN finalize for channel c == lane (redundant across waves)
    float wa[CI], b;
    {
        float w[CI];
#pragma unroll
        for (int i = 0; i < CI; ++i) w[i] = W[lane * CI + i];
        float mu = 0.f;
#pragma unroll
        for (int i = 0; i < CI; ++i) mu = fmaf(w[i], ws[MSTR * i], mu);
        mu *= inv_n;
        float ex2 = 0.f;
        int kk = 10;
#pragma unroll
        for (int i = 0; i < CI; ++i)
#pragma unroll
            for (int j = i; j < CI; ++j) {
                float mm = ws[MSTR * kk];
                float t = w[i] * w[j] * mm;
                ex2 += (i == j) ? t : 2.f * t;
                ++kk;
            }
        ex2 *= inv_n;
        float var = ex2 - mu * mu;
        float rstd = rsqrtf(var + BN_EPS);
        float a = rstd * gamma[lane];
        b = beta[lane] - mu * a;
#pragma unroll
        for (int i = 0; i < CI; ++i) wa[i] = a * w[i];
        if (wv == 0) {
            bsh[lane] = b;
#pragma unroll
            for (int i = 0; i < CI; ++i) wp[lane * CI + i] = wa[i];
        }
    }
    __syncthreads();   // tile staged + wp/bsh visible

    // ---- g partial: 125 pts/wave, 4-pt unroll, even/odd chain split
    float g0 = 0.f, g1 = 0.f, g2 = 0.f, g3 = 0.f;
    const int ps = wv * 125;

    auto ptdot = [&](int pp) -> float {      // relu(w.x_pp + b), 2 chains
        const float* r = &tile[pp * GS_LDR];
        float4 A = *(const float4*)r;
        float4 Bq = *(const float4*)(r + 4);
        float2 Cc = *(const float2*)(r + 8);
        float e = fmaf(wa[0], A.x, b);
        e = fmaf(wa[2], A.z, e);
        e = fmaf(wa[4], Bq.x, e);
        e = fmaf(wa[6], Bq.z, e);
        e = fmaf(wa[8], Cc.x, e);
        float o = wa[1] * A.y;
        o = fmaf(wa[3], A.w, o);
        o = fmaf(wa[5], Bq.y, o);
        o = fmaf(wa[7], Bq.w, o);
        o = fmaf(wa[9], Cc.y, o);
        return fmaxf(e + o, 0.f);
    };

#pragma unroll 1
    for (int p = ps; p + 4 <= ps + 124; p += 4) {   // 31 iterations
        g0 += ptdot(p);
        g1 += ptdot(p + 1);
        g2 += ptdot(p + 2);
        g3 += ptdot(p + 3);
    }
    g0 += ptdot(ps + 124);                   // tail (125 = 31*4 + 1)

    red[wv * 64 + lane] = (g0 + g1) + (g2 + g3);
    __syncthreads();
    if (tid < 64)
        atomicAdd(&ws[GOFF + GSTR * tid],
                  red[tid] + red[64 + tid] + red[128 + tid] + red[192 + tid]);

    // ---------------- last-block-done: inline prep ----------------
    __shared__ int lastf;
    __syncthreads();
    if (tid == 0) {
        __threadfence();
        int old = atomicAdd((int*)ws + CTRI, 1);
        lastf = (old == (int)gridDim.x - 1);
    }
    __syncthreads();
    if (!lastf) return;
    __threadfence();   // acquire: all blocks' g_sum adds visible

    __shared__ float T[C], XG[C];
    if (tid < 64)
        T[tid] = fmaxf(dw2[tid] * (ws[GOFF + GSTR * tid] * inv_n), 0.f);
    __syncthreads();
    if (tid < 64) {
        float acc = 0.f;
#pragma unroll
        for (int k = 0; k < C; ++k) acc = fmaf(pw2[tid * C + k], T[k], acc);
        XG[tid] = acc;
    }
    __syncthreads();

    if (tid < 64) {
        float4* FR = (float4*)(ws + FROFF);
        union { float4 f; s16x8 v; } u;

#pragma unroll
        for (int nt = 0; nt < 4; ++nt) {
            s16x8 tt;
#pragma unroll
            for (int j = 0; j < 8; ++j) {
                int k = 8 * q + j;
                tt[j] = (k < CI) ? f2bf(wp[(nt * 16 + m) * CI + k]) : (short)0;
            }
            u.v = tt; FR[nt * 64 + lane] = u.f;
        }
#pragma unroll
        for (int nt = 0; nt < 4; ++nt)
#pragma unroll
            for (int kc = 0; kc < 2; ++kc) {
                const float* src = pw1 + (nt * 16 + m) * C + kc * 32 + q * 8;
                float4 p0 = *(const float4*)src, p1 = *(const float4*)(src + 4);
                s16x8 tt;
                tt[0] = f2bf(p0.x); tt[1] = f2bf(p0.y); tt[2] = f2bf(p0.z); tt[3] = f2bf(p0.w);
                tt[4] = f2bf(p1.x); tt[5] = f2bf(p1.y); tt[6] = f2bf(p1.z); tt[7] = f2bf(p1.w);
                u.v = tt; FR[(4 + nt * 2 + kc) * 64 + lane] = u.f;
            }
        float4 f;
        f.x = bsh[m]; f.y = bsh[16 + m]; f.z = bsh[32 + m]; f.w = bsh[48 + m];
        FR[12 * 64 + lane] = f;
        f.x = dw1[m]; f.y = dw1[16 + m]; f.z = dw1[32 + m]; f.w = dw1[48 + m];
        FR[13 * 64 + lane] = f;
        f.x = XG[m]; f.y = XG[16 + m]; f.z = XG[32 + m]; f.w = XG[48 + m];
        FR[14 * 64 + lane] = f;
    }
}

// ---------------------------------------------------------------------------
// Kernel 3: k_main — EXACT round-0 structure (best measured: 91.6 us).
// One wave per 2 contiguous segments, 16-pt batches, single LDS tile +
// 2 lgkm fences/batch, 2-deep row prefetch, 7500 blocks x 128. FROZEN:
// all structural variants (32-pt interleave, SEGW=4, 4-wave blocks,
// 17KB-LDS double-buffer) measured worse (occupancy drops).
// ---------------------------------------------------------------------------
#define LD 68
#define SEGW 2
__global__ void __launch_bounds__(128) k_main(const float* __restrict__ inp,
                                              const float* __restrict__ ws,
                                              const int* __restrict__ starts,
                                              float* __restrict__ out) {
    const int tid  = threadIdx.x;
    const int wv   = tid >> 6;
    const int lane = tid & 63;
    const int m = lane & 15;
    const int q = lane >> 4;
    const f32x4 zero = {0.f, 0.f, 0.f, 0.f};

    const float4* FR = (const float4*)(ws + FROFF);
    union { float4 f; s16x8 v; } u;
    s16x8 wfr[4];
#pragma unroll
    for (int nt = 0; nt < 4; ++nt) { u.f = FR[nt * 64 + lane]; wfr[nt] = u.v; }
    s16x8 bfr[4][2];
#pragma unroll
    for (int nt = 0; nt < 4; ++nt)
#pragma unroll
        for (int kc = 0; kc < 2; ++kc) { u.f = FR[(4 + nt * 2 + kc) * 64 + lane]; bfr[nt][kc] = u.v; }
    const float4 bb4  = FR[12 * 64 + lane];
    const float4 d14  = FR[13 * 64 + lane];
    const float4 xg4  = FR[14 * 64 + lane];
    const float bb[4]  = {bb4.x, bb4.y, bb4.z, bb4.w};
    const float d1v[4] = {d14.x, d14.y, d14.z, d14.w};
    const float xgv[4] = {xg4.x, xg4.y, xg4.z, xg4.w};

    __shared__ float sb[2][16 * LD];
    float* my = sb[wv];

    const int w  = blockIdx.x * 2 + wv;    // 0..14999
    const int s0 = w * SEGW;

    int st1 = starts[s0 + 1];
    int st2 = (s0 + 2 < NSEG) ? starts[s0 + 2] : N_PTS;
    const int start   = starts[s0];
    const int end_all = st2;

    int cur = s0;
    int end_cur = st1;

    float sm[4]  = {0.f, 0.f, 0.f, 0.f};
    float mxv[4] = {-INFINITY, -INFINITY, -INFINITY, -INFINITY};

    auto flushseg = [&](int s) {
#pragma unroll
        for (int nt = 0; nt < 4; ++nt) {
            sm[nt] += __shfl_xor(sm[nt], 16, 64);
            sm[nt] += __shfl_xor(sm[nt], 32, 64);
            mxv[nt] = fmaxf(mxv[nt], __shfl_xor(mxv[nt], 16, 64));
            mxv[nt] = fmaxf(mxv[nt], __shfl_xor(mxv[nt], 32, 64));
        }
        float S = sm[0], M = mxv[0];
        if (q == 1) { S = sm[1]; M = mxv[1]; }
        if (q == 2) { S = sm[2]; M = mxv[2]; }
        if (q == 3) { S = sm[3]; M = mxv[3]; }
        out[(size_t)s * C + lane] = S + M;
#pragma unroll
        for (int nt = 0; nt < 4; ++nt) { sm[nt] = 0.f; mxv[nt] = -INFINITY; }
    };

    auto loadrows = [&](int pb) -> Rows {
        Rows R;
        R.r0 = R.r1 = R.r2 = R.r3 = make_float2(0.f, 0.f);
        const float* row = inp + (size_t)min(pb + m, N_PTS - 1) * CI;
        if (q == 0) {
            R.r0 = *(const float2*)(row);     R.r1 = *(const float2*)(row + 2);
            R.r2 = *(const float2*)(row + 4); R.r3 = *(const float2*)(row + 6);
        } else if (q == 1) {
            R.r0 = *(const float2*)(row + 8);
        }
        return R;
    };

    Rows A = loadrows(start);
    Rows B = (start + 16 < end_all) ? loadrows(start + 16) : A;

    for (int base = start; base < end_all; base += 16) {
        Rows L = A;
        A = B;
        if (base + 32 < end_all) B = loadrows(base + 32);

        const int nb = min(16, end_all - base);

        // ---- A-frag of rows (K padded to 32, truncation pack)
        union { s16x8 v; unsigned uu[4]; } t;
        t.v = s16x8{0, 0, 0, 0, 0, 0, 0, 0};
        if (q < 2) t.uu[0] = pack_trunc(L.r0.x, L.r0.y);
        if (q == 0) {
            t.uu[1] = pack_trunc(L.r1.x, L.r1.y);
            t.uu[2] = pack_trunc(L.r2.x, L.r2.y);
            t.uu[3] = pack_trunc(L.r3.x, L.r3.y);
        }

        // ---- x' = rows @ W'^T  (C-layout: ch=16nt+m, pt=4q+r)
        f32x4 xt[4];
#pragma unroll
        for (int nt = 0; nt < 4; ++nt)
            xt[nt] = __builtin_amdgcn_mfma_f32_16x16x32_bf16(t.v, wfr[nt], zero, 0, 0, 0);

        // ---- BN + ReLU + swish; sw -> LDS tile [pt][ch]
        float xn[4][4];
#pragma unroll
        for (int nt = 0; nt < 4; ++nt)
#pragma unroll
            for (int r = 0; r < 4; ++r) {
                float x = fmaxf(xt[nt][r] + bb[nt], 0.f);
                xn[nt][r] = x;
                float sg = x * d1v[nt];
                float sw = sg * frcp(1.f + __expf(-sg));
                my[(4 * q + r) * LD + nt * 16 + m] = sw;
            }
        lds_fence();

        // ---- A-frags of sw: lane(m,q) reads sw[pt=m][32kc+8q+j]
        s16x8 av[2];
#pragma unroll
        for (int kc = 0; kc < 2; ++kc) {
            const float* src = &my[m * LD + kc * 32 + q * 8];
            float4 p0 = *(const float4*)src;
            float4 p1 = *(const float4*)(src + 4);
            union { s16x8 v; unsigned uu[4]; } tt;
            tt.uu[0] = pack_trunc(p0.x, p0.y);
            tt.uu[1] = pack_trunc(p0.z, p0.w);
            tt.uu[2] = pack_trunc(p1.x, p1.y);
            tt.uu[3] = pack_trunc(p1.z, p1.w);
            av[kc] = tt.v;
        }

        // ---- xl = sw @ pw1^T (C-layout, aligned with xn)
        f32x4 xi[4];
#pragma unroll
        for (int nt = 0; nt < 4; ++nt) {
            xi[nt] = __builtin_amdgcn_mfma_f32_16x16x32_bf16(av[0], bfr[nt][0], zero, 0, 0, 0);
            xi[nt] = __builtin_amdgcn_mfma_f32_16x16x32_bf16(av[1], bfr[nt][1], xi[nt], 0, 0, 0);
        }
        lds_fence();   // reads drained before next batch overwrites the tile

#pragma unroll
        for (int nt = 0; nt < 4; ++nt)
#pragma unroll
            for (int r = 0; r < 4; ++r) {
                float v   = xi[nt][r] + xgv[nt];
                float wei = frcp(1.f + __expf(-v));
                float x   = xn[nt][r];
                xi[nt][r] = fmaf(x, wei, x);
            }

        // ---- segmented accumulate (<=1 boundary per batch: min seg len 33)
        const int fin = base + nb;
        if (fin <= end_cur) {
            if (nb == 16) {
#pragma unroll
                for (int nt = 0; nt < 4; ++nt)
#pragma unroll
                    for (int r = 0; r < 4; ++r) {
                        sm[nt] += xi[nt][r];
                        mxv[nt] = fmaxf(mxv[nt], xi[nt][r]);
                    }
            } else {
#pragma unroll
                for (int nt = 0; nt < 4; ++nt)
#pragma unroll
                    for (int r = 0; r < 4; ++r) {
                        bool act = (4 * q + r) < nb;
                        sm[nt] += act ? xi[nt][r] : 0.f;
                        mxv[nt] = fmaxf(mxv[nt], act ? xi[nt][r] : -INFINITY);
                    }
            }
            if (fin == end_cur) { flushseg(cur); ++cur; end_cur = st2; }
        } else {
            const int B = end_cur - base;   // 1..nb-1
#pragma unroll
            for (int nt = 0; nt < 4; ++nt)
#pragma unroll
                for (int r = 0; r < 4; ++r) {
                    bool act = (4 * q + r) < B;
                    sm[nt] += act ? xi[nt][r] : 0.f;
                    mxv[nt] = fmaxf(mxv[nt], act ? xi[nt][r] : -INFINITY);
                }
            flushseg(cur); ++cur;
#pragma unroll
            for (int nt = 0; nt < 4; ++nt)
#pragma unroll
                for (int r = 0; r < 4; ++r) {
                    int pt = 4 * q + r;
                    bool act = (pt >= B) && (pt < nb);
                    sm[nt] += act ? xi[nt][r] : 0.f;
                    mxv[nt] = fmaxf(mxv[nt], act ? xi[nt][r] : -INFINITY);
                }
            end_cur = st2;
        }
    }
}

extern "C" void kernel_launch(void* const* d_in, const int* in_sizes, int n_in,
                              void* d_out, int out_size, void* d_ws, size_t ws_size,
                              hipStream_t stream) {
    const float* inp   = (const float*)d_in[0];
    const int*   unq   = (const int*)d_in[1];
    const float* W     = (const float*)d_in[2];
    const float* gamma = (const float*)d_in[3];
    const float* beta  = (const float*)d_in[4];
    const float* dw1   = (const float*)d_in[5];
    const float* pw1   = (const float*)d_in[6];
    const float* dw2   = (const float*)d_in[7];
    const float* pw2   = (const float*)d_in[8];
    float* out = (float*)d_out;
    float* ws  = (float*)d_ws;
    int* starts = (int*)ws + 1024;

    hipMemsetAsync(ws, 0, 1024 * sizeof(float), stream);   // zero accumulators+ctr

    k_moments <<<1024, 256, 0, stream>>>(inp, unq, ws, starts);
    k_gstats  <<<2000, 256, 0, stream>>>(inp, W, gamma, beta, dw1, pw1, dw2, pw2, ws);
    k_main    <<<7500, 128, 0, stream>>>(inp, ws, starts, out);
}

// Round 19
// 283.208 us; speedup vs baseline: 1.0531x; 1.0451x over previous
//
#include <hip/hip_runtime.h>
#include <math.h>

#define N_PTS   1000000
#define CI      10
#define C       64
#define NSEG    30000
#define BN_EPS  1e-3f
#define FROFF   31104      // float index of fragment blob (after starts ints)

// ws layout (floats):
// moments: scalar k at ws[7*k], k<65   (stride-7 floats spreads atomic fan-in)
// g_sum:   channel c at ws[512 + 8*c]
// int slot 961: block-done counter for k_gstats last-block prep (memset-zeroed)
// ints at [1024:31024): segment starts
// [FROFF : FROFF+15*256): per-lane fragment blob, 15 items x 64 lanes x 16B
#define MSTR 7
#define GOFF 512
#define GSTR 8
#define CTRI 961

using f32x4 = __attribute__((ext_vector_type(4))) float;
using s16x8 = __attribute__((ext_vector_type(8))) short;

__device__ inline short f2bf(float x) {           // RNE fp32 -> bf16 (weights)
    unsigned u = __float_as_uint(x);
    unsigned r = (u + 0x7fffu + ((u >> 16) & 1u)) >> 16;
    return (short)r;
}
__device__ inline unsigned pack_trunc(float lo, float hi) {  // 2x bf16 truncate
    return (__float_as_uint(hi) & 0xffff0000u) | (__float_as_uint(lo) >> 16);
}
__device__ inline float frcp(float x) { return __builtin_amdgcn_rcpf(x); }
// LDS-only drain: write->read visibility within a wave, does NOT drain vmcnt
__device__ inline void lds_fence() {
    asm volatile("s_waitcnt lgkmcnt(0)" ::: "memory");
}
// VALU-pipe lane broadcast (uniform index) — avoids LDS/ds_bpermute entirely
__device__ inline float bcastlane(float x, int l) {
    return __int_as_float(__builtin_amdgcn_readlane(__float_as_int(x), l));
}

struct Rows { float2 r0, r1, r2, r3; };

// Kernel 1: colsum[10] + second-moment M[55] of raw inputs. Fused: segment
// starts. 1-deep software prefetch of rows+idx; line-spread atomics.
__global__ void __launch_bounds__(256) k_moments(const float* __restrict__ inp,
                                                 const int* __restrict__ idx,
                                                 float* __restrict__ ws,
                                                 int* __restrict__ starts) {
    const int tid = threadIdx.x;
    const int stride = gridDim.x * blockDim.x;
    float v[65];
#pragma unroll
    for (int k = 0; k < 65; ++k) v[k] = 0.f;

    int p = blockIdx.x * blockDim.x + tid;
    float2 a0, a1, a2, a3, a4;
    int ic = 0, ip = 0;
    auto ld = [&](int qq) {
        const float2* r2 = (const float2*)(inp + (size_t)qq * CI);
        a0 = r2[0]; a1 = r2[1]; a2 = r2[2]; a3 = r2[3]; a4 = r2[4];
        ic = idx[qq]; ip = (qq > 0) ? idx[qq - 1] : ic;
    };
    if (p < N_PTS) ld(p);
    while (p < N_PTS) {
        float r[CI] = {a0.x, a0.y, a1.x, a1.y, a2.x, a2.y, a3.x, a3.y, a4.x, a4.y};
        const int cc = ic, cp = ip, cq = p;
        const int pn = p + stride;
        if (pn < N_PTS) ld(pn);                       // prefetch next point

#pragma unroll
        for (int i = 0; i < CI; ++i) v[i] += r[i];
        int kk = 10;
#pragma unroll
        for (int i = 0; i < CI; ++i)
#pragma unroll
            for (int j = i; j < CI; ++j) { v[kk] = fmaf(r[i], r[j], v[kk]); ++kk; }

        if (cq == 0) starts[0] = 0;
        else if (cp != cc) starts[cc] = cq;
        p = pn;
    }

#pragma unroll
    for (int k = 0; k < 65; ++k) {
#pragma unroll
        for (int off = 32; off >= 1; off >>= 1)
            v[k] += __shfl_xor(v[k], off, 64);
    }
    __shared__ float red[4 * 65];
    const int wv = tid >> 6, ln = tid & 63;
    if (ln == 0) {
#pragma unroll
        for (int k = 0; k < 65; ++k) red[wv * 65 + k] = v[k];
    }
    __syncthreads();
    if (tid < 65)
        atomicAdd(&ws[MSTR * tid],
                  red[tid] + red[65 + tid] + red[130 + tid] + red[195 + tid]);
}

// ---------------------------------------------------------------------------
// Kernel 2: k_gstats v4 — NO LDS in the hot loop. v2/v3 both landed ~90 us:
// LDS-pipe throughput bound (row broadcast = 2 b128 + 1 b64 = ~30 LDS-cyc/pt
// per wave; the arithmetic reproduces 89.5 us). v4: lane = channel with
// weights in VGPRs (as before), but each lane also loads ITS OWN point's row
// (coalesced; 64 points per wave batch; 1M/64 = 15625 exact batches), then
// broadcasts rows across lanes via v_readlane (VALU pipe, uniform index).
// 22 VALU ops/pt -> issue-bound ~18 us + HBM overlap. 1-deep batch prefetch.
// Last block (atomic counter, device fence) runs the former k_prep inline.
// ---------------------------------------------------------------------------
__global__ void __launch_bounds__(256) k_gstats(const float* __restrict__ inp,
                                                const float* __restrict__ W,
                                                const float* __restrict__ gamma,
                                                const float* __restrict__ beta,
                                                const float* __restrict__ dw1,
                                                const float* __restrict__ pw1,
                                                const float* __restrict__ dw2,
                                                const float* __restrict__ pw2,
                                                float* __restrict__ ws) {
    const int tid  = threadIdx.x;
    const int wv   = tid >> 6;
    const int lane = tid & 63;
    const int m = lane & 15;
    const int q = lane >> 4;
    const float inv_n = 1.f / (float)N_PTS;

    __shared__ float wp[C * CI];             // W' = a*W (for last-block prep)
    __shared__ float bsh[C];
    __shared__ float red[4 * 64];

    // ---- per-lane BN finalize for channel c == lane (redundant across waves)
    float wa[CI], b;
    {
        float w[CI];
#pragma unroll
        for (int i = 0; i < CI; ++i) w[i] = W[lane * CI + i];
        float mu = 0.f;
#pragma unroll
        for (int i = 0; i < CI; ++i) mu = fmaf(w[i], ws[MSTR * i], mu);
        mu *= inv_n;
        float ex2 = 0.f;
        int kk = 10;
#pragma unroll
        for (int i = 0; i < CI; ++i)
#pragma unroll
            for (int j = i; j < CI; ++j) {
                float mm = ws[MSTR * kk];
                float t = w[i] * w[j] * mm;
                ex2 += (i == j) ? t : 2.f * t;
                ++kk;
            }
        ex2 *= inv_n;
        float var = ex2 - mu * mu;
        float rstd = rsqrtf(var + BN_EPS);
        float a = rstd * gamma[lane];
        b = beta[lane] - mu * a;
#pragma unroll
        for (int i = 0; i < CI; ++i) wa[i] = a * w[i];
        if (wv == 0) {
            bsh[lane] = b;
#pragma unroll
            for (int i = 0; i < CI; ++i) wp[lane * CI + i] = wa[i];
        }
    }

    // ---- batches of 64 points per wave; lane owns one row per batch
    const int wid = blockIdx.x * 4 + wv;
    const int nw  = gridDim.x * 4;
    const int NBATCH = N_PTS / 64;           // 15625 exact, no tail

    float r0[CI], r1[CI];
    auto ldrow = [&](float* r, int bt) {
        const float2* s = (const float2*)(inp + ((size_t)bt * 64 + lane) * CI);
        float2 x0 = s[0], x1 = s[1], x2 = s[2], x3 = s[3], x4 = s[4];
        r[0] = x0.x; r[1] = x0.y; r[2] = x1.x; r[3] = x1.y; r[4] = x2.x;
        r[5] = x2.y; r[6] = x3.x; r[7] = x3.y; r[8] = x4.x; r[9] = x4.y;
    };

    float g0 = 0.f, g1 = 0.f;
    if (wid < NBATCH) ldrow(r0, wid);
    for (int bt = wid; bt < NBATCH; bt += nw) {
        if (bt + nw < NBATCH) ldrow(r1, bt + nw);   // prefetch next batch

#pragma unroll 4
        for (int p = 0; p < 64; p += 2) {
            float acc0 = b, acc1 = b;
#pragma unroll
            for (int i = 0; i < CI; ++i) {
                acc0 = fmaf(wa[i], bcastlane(r0[i], p), acc0);
                acc1 = fmaf(wa[i], bcastlane(r0[i], p + 1), acc1);
            }
            g0 += fmaxf(acc0, 0.f);
            g1 += fmaxf(acc1, 0.f);
        }
#pragma unroll
        for (int i = 0; i < CI; ++i) r0[i] = r1[i];
    }

    red[wv * 64 + lane] = g0 + g1;           // lane == channel
    __syncthreads();
    if (tid < 64)
        atomicAdd(&ws[GOFF + GSTR * tid],
                  red[tid] + red[64 + tid] + red[128 + tid] + red[192 + tid]);

    // ---------------- last-block-done: inline prep ----------------
    __shared__ int lastf;
    __syncthreads();
    if (tid == 0) {
        __threadfence();
        int old = atomicAdd((int*)ws + CTRI, 1);
        lastf = (old == (int)gridDim.x - 1);
    }
    __syncthreads();
    if (!lastf) return;
    __threadfence();   // acquire: all blocks' g_sum adds visible

    __shared__ float T[C], XG[C];
    if (tid < 64)
        T[tid] = fmaxf(dw2[tid] * (ws[GOFF + GSTR * tid] * inv_n), 0.f);
    __syncthreads();
    if (tid < 64) {
        float acc = 0.f;
#pragma unroll
        for (int k = 0; k < C; ++k) acc = fmaf(pw2[tid * C + k], T[k], acc);
        XG[tid] = acc;
    }
    __syncthreads();

    if (tid < 64) {
        float4* FR = (float4*)(ws + FROFF);
        union { float4 f; s16x8 v; } u;

#pragma unroll
        for (int nt = 0; nt < 4; ++nt) {
            s16x8 tt;
#pragma unroll
            for (int j = 0; j < 8; ++j) {
                int k = 8 * q + j;
                tt[j] = (k < CI) ? f2bf(wp[(nt * 16 + m) * CI + k]) : (short)0;
            }
            u.v = tt; FR[nt * 64 + lane] = u.f;
        }
#pragma unroll
        for (int nt = 0; nt < 4; ++nt)
#pragma unroll
            for (int kc = 0; kc < 2; ++kc) {
                const float* src = pw1 + (nt * 16 + m) * C + kc * 32 + q * 8;
                float4 p0 = *(const float4*)src, p1 = *(const float4*)(src + 4);
                s16x8 tt;
                tt[0] = f2bf(p0.x); tt[1] = f2bf(p0.y); tt[2] = f2bf(p0.z); tt[3] = f2bf(p0.w);
                tt[4] = f2bf(p1.x); tt[5] = f2bf(p1.y); tt[6] = f2bf(p1.z); tt[7] = f2bf(p1.w);
                u.v = tt; FR[(4 + nt * 2 + kc) * 64 + lane] = u.f;
            }
        float4 f;
        f.x = bsh[m]; f.y = bsh[16 + m]; f.z = bsh[32 + m]; f.w = bsh[48 + m];
        FR[12 * 64 + lane] = f;
        f.x = dw1[m]; f.y = dw1[16 + m]; f.z = dw1[32 + m]; f.w = dw1[48 + m];
        FR[13 * 64 + lane] = f;
        f.x = XG[m]; f.y = XG[16 + m]; f.z = XG[32 + m]; f.w = XG[48 + m];
        FR[14 * 64 + lane] = f;
    }
}

// ---------------------------------------------------------------------------
// Kernel 3: k_main — EXACT round-0 structure (best measured: 89-92 us).
// One wave per 2 contiguous segments, 16-pt batches, single LDS tile +
// 2 lgkm fences/batch, 2-deep row prefetch, 7500 blocks x 128. FROZEN:
// all structural variants (32-pt interleave, SEGW=4, 4-wave blocks,
// 17KB-LDS double-buffer) measured worse (occupancy drops).
// ---------------------------------------------------------------------------
#define LD 68
#define SEGW 2
__global__ void __launch_bounds__(128) k_main(const float* __restrict__ inp,
                                              const float* __restrict__ ws,
                                              const int* __restrict__ starts,
                                              float* __restrict__ out) {
    const int tid  = threadIdx.x;
    const int wv   = tid >> 6;
    const int lane = tid & 63;
    const int m = lane & 15;
    const int q = lane >> 4;
    const f32x4 zero = {0.f, 0.f, 0.f, 0.f};

    const float4* FR = (const float4*)(ws + FROFF);
    union { float4 f; s16x8 v; } u;
    s16x8 wfr[4];
#pragma unroll
    for (int nt = 0; nt < 4; ++nt) { u.f = FR[nt * 64 + lane]; wfr[nt] = u.v; }
    s16x8 bfr[4][2];
#pragma unroll
    for (int nt = 0; nt < 4; ++nt)
#pragma unroll
        for (int kc = 0; kc < 2; ++kc) { u.f = FR[(4 + nt * 2 + kc) * 64 + lane]; bfr[nt][kc] = u.v; }
    const float4 bb4  = FR[12 * 64 + lane];
    const float4 d14  = FR[13 * 64 + lane];
    const float4 xg4  = FR[14 * 64 + lane];
    const float bb[4]  = {bb4.x, bb4.y, bb4.z, bb4.w};
    const float d1v[4] = {d14.x, d14.y, d14.z, d14.w};
    const float xgv[4] = {xg4.x, xg4.y, xg4.z, xg4.w};

    __shared__ float sb[2][16 * LD];
    float* my = sb[wv];

    const int w  = blockIdx.x * 2 + wv;    // 0..14999
    const int s0 = w * SEGW;

    int st1 = starts[s0 + 1];
    int st2 = (s0 + 2 < NSEG) ? starts[s0 + 2] : N_PTS;
    const int start   = starts[s0];
    const int end_all = st2;

    int cur = s0;
    int end_cur = st1;

    float sm[4]  = {0.f, 0.f, 0.f, 0.f};
    float mxv[4] = {-INFINITY, -INFINITY, -INFINITY, -INFINITY};

    auto flushseg = [&](int s) {
#pragma unroll
        for (int nt = 0; nt < 4; ++nt) {
            sm[nt] += __shfl_xor(sm[nt], 16, 64);
            sm[nt] += __shfl_xor(sm[nt], 32, 64);
            mxv[nt] = fmaxf(mxv[nt], __shfl_xor(mxv[nt], 16, 64));
            mxv[nt] = fmaxf(mxv[nt], __shfl_xor(mxv[nt], 32, 64));
        }
        float S = sm[0], M = mxv[0];
        if (q == 1) { S = sm[1]; M = mxv[1]; }
        if (q == 2) { S = sm[2]; M = mxv[2]; }
        if (q == 3) { S = sm[3]; M = mxv[3]; }
        out[(size_t)s * C + lane] = S + M;
#pragma unroll
        for (int nt = 0; nt < 4; ++nt) { sm[nt] = 0.f; mxv[nt] = -INFINITY; }
    };

    auto loadrows = [&](int pb) -> Rows {
        Rows R;
        R.r0 = R.r1 = R.r2 = R.r3 = make_float2(0.f, 0.f);
        const float* row = inp + (size_t)min(pb + m, N_PTS - 1) * CI;
        if (q == 0) {
            R.r0 = *(const float2*)(row);     R.r1 = *(const float2*)(row + 2);
            R.r2 = *(const float2*)(row + 4); R.r3 = *(const float2*)(row + 6);
        } else if (q == 1) {
            R.r0 = *(const float2*)(row + 8);
        }
        return R;
    };

    Rows A = loadrows(start);
    Rows B = (start + 16 < end_all) ? loadrows(start + 16) : A;

    for (int base = start; base < end_all; base += 16) {
        Rows L = A;
        A = B;
        if (base + 32 < end_all) B = loadrows(base + 32);

        const int nb = min(16, end_all - base);

        // ---- A-frag of rows (K padded to 32, truncation pack)
        union { s16x8 v; unsigned uu[4]; } t;
        t.v = s16x8{0, 0, 0, 0, 0, 0, 0, 0};
        if (q < 2) t.uu[0] = pack_trunc(L.r0.x, L.r0.y);
        if (q == 0) {
            t.uu[1] = pack_trunc(L.r1.x, L.r1.y);
            t.uu[2] = pack_trunc(L.r2.x, L.r2.y);
            t.uu[3] = pack_trunc(L.r3.x, L.r3.y);
        }

        // ---- x' = rows @ W'^T  (C-layout: ch=16nt+m, pt=4q+r)
        f32x4 xt[4];
#pragma unroll
        for (int nt = 0; nt < 4; ++nt)
            xt[nt] = __builtin_amdgcn_mfma_f32_16x16x32_bf16(t.v, wfr[nt], zero, 0, 0, 0);

        // ---- BN + ReLU + swish; sw -> LDS tile [pt][ch]
        float xn[4][4];
#pragma unroll
        for (int nt = 0; nt < 4; ++nt)
#pragma unroll
            for (int r = 0; r < 4; ++r) {
                float x = fmaxf(xt[nt][r] + bb[nt], 0.f);
                xn[nt][r] = x;
                float sg = x * d1v[nt];
                float sw = sg * frcp(1.f + __expf(-sg));
                my[(4 * q + r) * LD + nt * 16 + m] = sw;
            }
        lds_fence();

        // ---- A-frags of sw: lane(m,q) reads sw[pt=m][32kc+8q+j]
        s16x8 av[2];
#pragma unroll
        for (int kc = 0; kc < 2; ++kc) {
            const float* src = &my[m * LD + kc * 32 + q * 8];
            float4 p0 = *(const float4*)src;
            float4 p1 = *(const float4*)(src + 4);
            union { s16x8 v; unsigned uu[4]; } tt;
            tt.uu[0] = pack_trunc(p0.x, p0.y);
            tt.uu[1] = pack_trunc(p0.z, p0.w);
            tt.uu[2] = pack_trunc(p1.x, p1.y);
            tt.uu[3] = pack_trunc(p1.z, p1.w);
            av[kc] = tt.v;
        }

        // ---- xl = sw @ pw1^T (C-layout, aligned with xn)
        f32x4 xi[4];
#pragma unroll
        for (int nt = 0; nt < 4; ++nt) {
            xi[nt] = __builtin_amdgcn_mfma_f32_16x16x32_bf16(av[0], bfr[nt][0], zero, 0, 0, 0);
            xi[nt] = __builtin_amdgcn_mfma_f32_16x16x32_bf16(av[1], bfr[nt][1], xi[nt], 0, 0, 0);
        }
        lds_fence();   // reads drained before next batch overwrites the tile

#pragma unroll
        for (int nt = 0; nt < 4; ++nt)
#pragma unroll
            for (int r = 0; r < 4; ++r) {
                float v   = xi[nt][r] + xgv[nt];
                float wei = frcp(1.f + __expf(-v));
                float x   = xn[nt][r];
                xi[nt][r] = fmaf(x, wei, x);
            }

        // ---- segmented accumulate (<=1 boundary per batch: min seg len 33)
        const int fin = base + nb;
        if (fin <= end_cur) {
            if (nb == 16) {
#pragma unroll
                for (int nt = 0; nt < 4; ++nt)
#pragma unroll
                    for (int r = 0; r < 4; ++r) {
                        sm[nt] += xi[nt][r];
                        mxv[nt] = fmaxf(mxv[nt], xi[nt][r]);
                    }
            } else {
#pragma unroll
                for (int nt = 0; nt < 4; ++nt)
#pragma unroll
                    for (int r = 0; r < 4; ++r) {
                        bool act = (4 * q + r) < nb;
                        sm[nt] += act ? xi[nt][r] : 0.f;
                        mxv[nt] = fmaxf(mxv[nt], act ? xi[nt][r] : -INFINITY);
                    }
            }
            if (fin == end_cur) { flushseg(cur); ++cur; end_cur = st2; }
        } else {
            const int B = end_cur - base;   // 1..nb-1
#pragma unroll
            for (int nt = 0; nt < 4; ++nt)
#pragma unroll
                for (int r = 0; r < 4; ++r) {
                    bool act = (4 * q + r) < B;
                    sm[nt] += act ? xi[nt][r] : 0.f;
                    mxv[nt] = fmaxf(mxv[nt], act ? xi[nt][r] : -INFINITY);
                }
            flushseg(cur); ++cur;
#pragma unroll
            for (int nt = 0; nt < 4; ++nt)
#pragma unroll
                for (int r = 0; r < 4; ++r) {
                    int pt = 4 * q + r;
                    bool act = (pt >= B) && (pt < nb);
                    sm[nt] += act ? xi[nt][r] : 0.f;
                    mxv[nt] = fmaxf(mxv[nt], act ? xi[nt][r] : -INFINITY);
                }
            end_cur = st2;
        }
    }
}

extern "C" void kernel_launch(void* const* d_in, const int* in_sizes, int n_in,
                              void* d_out, int out_size, void* d_ws, size_t ws_size,
                              hipStream_t stream) {
    const float* inp   = (const float*)d_in[0];
    const int*   unq   = (const int*)d_in[1];
    const float* W     = (const float*)d_in[2];
    const float* gamma = (const float*)d_in[3];
    const float* beta  = (const float*)d_in[4];
    const float* dw1   = (const float*)d_in[5];
    const float* pw1   = (const float*)d_in[6];
    const float* dw2   = (const float*)d_in[7];
    const float* pw2   = (const float*)d_in[8];
    float* out = (float*)d_out;
    float* ws  = (float*)d_ws;
    int* starts = (int*)ws + 1024;

    hipMemsetAsync(ws, 0, 1024 * sizeof(float), stream);   // zero accumulators+ctr

    k_moments <<<1024, 256, 0, stream>>>(inp, unq, ws, starts);
    k_gstats  <<<1024, 256, 0, stream>>>(inp, W, gamma, beta, dw1, pw1, dw2, pw2, ws);
    k_main    <<<7500, 128, 0, stream>>>(inp, ws, starts, out);
}

// Round 22
// 280.345 us; speedup vs baseline: 1.0638x; 1.0102x over previous
//
#include <hip/hip_runtime.h>
#include <math.h>

#define N_PTS   1000000
#define CI      10
#define C       64
#define NSEG    30000
#define BN_EPS  1e-3f
#define FROFF   31104      // float index of fragment blob (after starts ints)

// ws layout (floats):
// moments: scalar k at ws[7*k], k<65   (stride-7 floats spreads atomic fan-in)
// g_sum:   channel c at ws[512 + 8*c]
// int slot 961: block-done counter for k_gstats last-block prep (memset-zeroed)
// ints at [1024:31024): segment starts
// [FROFF : FROFF+15*256): per-lane fragment blob, 15 items x 64 lanes x 16B
#define MSTR 7
#define GOFF 512
#define GSTR 8
#define CTRI 961

using f32x4 = __attribute__((ext_vector_type(4))) float;
using s16x8 = __attribute__((ext_vector_type(8))) short;

__device__ inline short f2bf(float x) {           // RNE fp32 -> bf16 (weights)
    unsigned u = __float_as_uint(x);
    unsigned r = (u + 0x7fffu + ((u >> 16) & 1u)) >> 16;
    return (short)r;
}
__device__ inline unsigned pack_trunc(float lo, float hi) {  // 2x bf16 truncate
    return (__float_as_uint(hi) & 0xffff0000u) | (__float_as_uint(lo) >> 16);
}
__device__ inline float frcp(float x) { return __builtin_amdgcn_rcpf(x); }
// LDS-only drain: write->read visibility within a wave, does NOT drain vmcnt
__device__ inline void lds_fence() {
    asm volatile("s_waitcnt lgkmcnt(0)" ::: "memory");
}
// VALU-pipe lane broadcast (uniform index) — avoids LDS/ds_bpermute entirely
__device__ inline float bcastlane(float x, int l) {
    return __int_as_float(__builtin_amdgcn_readlane(__float_as_int(x), l));
}

struct Rows { float2 r0, r1, r2, r3; };

// Kernel 1: colsum[10] + second-moment M[55] of raw inputs. Fused: segment
// starts. 1-deep software prefetch of rows+idx; line-spread atomics.
__global__ void __launch_bounds__(256) k_moments(const float* __restrict__ inp,
                                                 const int* __restrict__ idx,
                                                 float* __restrict__ ws,
                                                 int* __restrict__ starts) {
    const int tid = threadIdx.x;
    const int stride = gridDim.x * blockDim.x;
    float v[65];
#pragma unroll
    for (int k = 0; k < 65; ++k) v[k] = 0.f;

    int p = blockIdx.x * blockDim.x + tid;
    float2 a0, a1, a2, a3, a4;
    int ic = 0, ip = 0;
    auto ld = [&](int qq) {
        const float2* r2 = (const float2*)(inp + (size_t)qq * CI);
        a0 = r2[0]; a1 = r2[1]; a2 = r2[2]; a3 = r2[3]; a4 = r2[4];
        ic = idx[qq]; ip = (qq > 0) ? idx[qq - 1] : ic;
    };
    if (p < N_PTS) ld(p);
    while (p < N_PTS) {
        float r[CI] = {a0.x, a0.y, a1.x, a1.y, a2.x, a2.y, a3.x, a3.y, a4.x, a4.y};
        const int cc = ic, cp = ip, cq = p;
        const int pn = p + stride;
        if (pn < N_PTS) ld(pn);                       // prefetch next point

#pragma unroll
        for (int i = 0; i < CI; ++i) v[i] += r[i];
        int kk = 10;
#pragma unroll
        for (int i = 0; i < CI; ++i)
#pragma unroll
            for (int j = i; j < CI; ++j) { v[kk] = fmaf(r[i], r[j], v[kk]); ++kk; }

        if (cq == 0) starts[0] = 0;
        else if (cp != cc) starts[cc] = cq;
        p = pn;
    }

#pragma unroll
    for (int k = 0; k < 65; ++k) {
#pragma unroll
        for (int off = 32; off >= 1; off >>= 1)
            v[k] += __shfl_xor(v[k], off, 64);
    }
    __shared__ float red[4 * 65];
    const int wv = tid >> 6, ln = tid & 63;
    if (ln == 0) {
#pragma unroll
        for (int k = 0; k < 65; ++k) red[wv * 65 + k] = v[k];
    }
    __syncthreads();
    if (tid < 65)
        atomicAdd(&ws[MSTR * tid],
                  red[tid] + red[65 + tid] + red[130 + tid] + red[195 + tid]);
}

// ---------------------------------------------------------------------------
// Kernel 2: k_gstats v4 (MEASURED GOOD round 19: dropped out of top-5, i.e.
// < 89.9 us vs 89.4 before). NO LDS in hot loop: lane = channel, weights in
// VGPRs; each lane loads ITS OWN point's row (coalesced, 64 pts/wave batch,
// 1M/64 = 15625 exact), rows broadcast across lanes via v_readlane (VALU
// pipe). 1-deep batch prefetch. Last block runs the former k_prep inline.
// FROZEN.
// ---------------------------------------------------------------------------
__global__ void __launch_bounds__(256) k_gstats(const float* __restrict__ inp,
                                                const float* __restrict__ W,
                                                const float* __restrict__ gamma,
                                                const float* __restrict__ beta,
                                                const float* __restrict__ dw1,
                                                const float* __restrict__ pw1,
                                                const float* __restrict__ dw2,
                                                const float* __restrict__ pw2,
                                                float* __restrict__ ws) {
    const int tid  = threadIdx.x;
    const int wv   = tid >> 6;
    const int lane = tid & 63;
    const int m = lane & 15;
    const int q = lane >> 4;
    const float inv_n = 1.f / (float)N_PTS;

    __shared__ float wp[C * CI];             // W' = a*W (for last-block prep)
    __shared__ float bsh[C];
    __shared__ float red[4 * 64];

    // ---- per-lane BN finalize for channel c == lane (redundant across waves)
    float wa[CI], b;
    {
        float w[CI];
#pragma unroll
        for (int i = 0; i < CI; ++i) w[i] = W[lane * CI + i];
        float mu = 0.f;
#pragma unroll
        for (int i = 0; i < CI; ++i) mu = fmaf(w[i], ws[MSTR * i], mu);
        mu *= inv_n;
        float ex2 = 0.f;
        int kk = 10;
#pragma unroll
        for (int i = 0; i < CI; ++i)
#pragma unroll
            for (int j = i; j < CI; ++j) {
                float mm = ws[MSTR * kk];
                float t = w[i] * w[j] * mm;
                ex2 += (i == j) ? t : 2.f * t;
                ++kk;
            }
        ex2 *= inv_n;
        float var = ex2 - mu * mu;
        float rstd = rsqrtf(var + BN_EPS);
        float a = rstd * gamma[lane];
        b = beta[lane] - mu * a;
#pragma unroll
        for (int i = 0; i < CI; ++i) wa[i] = a * w[i];
        if (wv == 0) {
            bsh[lane] = b;
#pragma unroll
            for (int i = 0; i < CI; ++i) wp[lane * CI + i] = wa[i];
        }
    }

    // ---- batches of 64 points per wave; lane owns one row per batch
    const int wid = blockIdx.x * 4 + wv;
    const int nw  = gridDim.x * 4;
    const int NBATCH = N_PTS / 64;           // 15625 exact, no tail

    float r0[CI], r1[CI];
    auto ldrow = [&](float* r, int bt) {
        const float2* s = (const float2*)(inp + ((size_t)bt * 64 + lane) * CI);
        float2 x0 = s[0], x1 = s[1], x2 = s[2], x3 = s[3], x4 = s[4];
        r[0] = x0.x; r[1] = x0.y; r[2] = x1.x; r[3] = x1.y; r[4] = x2.x;
        r[5] = x2.y; r[6] = x3.x; r[7] = x3.y; r[8] = x4.x; r[9] = x4.y;
    };

    float g0 = 0.f, g1 = 0.f;
    if (wid < NBATCH) ldrow(r0, wid);
    for (int bt = wid; bt < NBATCH; bt += nw) {
        if (bt + nw < NBATCH) ldrow(r1, bt + nw);   // prefetch next batch

#pragma unroll 4
        for (int p = 0; p < 64; p += 2) {
            float acc0 = b, acc1 = b;
#pragma unroll
            for (int i = 0; i < CI; ++i) {
                acc0 = fmaf(wa[i], bcastlane(r0[i], p), acc0);
                acc1 = fmaf(wa[i], bcastlane(r0[i], p + 1), acc1);
            }
            g0 += fmaxf(acc0, 0.f);
            g1 += fmaxf(acc1, 0.f);
        }
#pragma unroll
        for (int i = 0; i < CI; ++i) r0[i] = r1[i];
    }

    red[wv * 64 + lane] = g0 + g1;           // lane == channel
    __syncthreads();
    if (tid < 64)
        atomicAdd(&ws[GOFF + GSTR * tid],
                  red[tid] + red[64 + tid] + red[128 + tid] + red[192 + tid]);

    // ---------------- last-block-done: inline prep ----------------
    __shared__ int lastf;
    __syncthreads();
    if (tid == 0) {
        __threadfence();
        int old = atomicAdd((int*)ws + CTRI, 1);
        lastf = (old == (int)gridDim.x - 1);
    }
    __syncthreads();
    if (!lastf) return;
    __threadfence();   // acquire: all blocks' g_sum adds visible

    __shared__ float T[C], XG[C];
    if (tid < 64)
        T[tid] = fmaxf(dw2[tid] * (ws[GOFF + GSTR * tid] * inv_n), 0.f);
    __syncthreads();
    if (tid < 64) {
        float acc = 0.f;
#pragma unroll
        for (int k = 0; k < C; ++k) acc = fmaf(pw2[tid * C + k], T[k], acc);
        XG[tid] = acc;
    }
    __syncthreads();

    if (tid < 64) {
        float4* FR = (float4*)(ws + FROFF);
        union { float4 f; s16x8 v; } u;

#pragma unroll
        for (int nt = 0; nt < 4; ++nt) {
            s16x8 tt;
#pragma unroll
            for (int j = 0; j < 8; ++j) {
                int k = 8 * q + j;
                tt[j] = (k < CI) ? f2bf(wp[(nt * 16 + m) * CI + k]) : (short)0;
            }
            u.v = tt; FR[nt * 64 + lane] = u.f;
        }
#pragma unroll
        for (int nt = 0; nt < 4; ++nt)
#pragma unroll
            for (int kc = 0; kc < 2; ++kc) {
                const float* src = pw1 + (nt * 16 + m) * C + kc * 32 + q * 8;
                float4 p0 = *(const float4*)src, p1 = *(const float4*)(src + 4);
                s16x8 tt;
                tt[0] = f2bf(p0.x); tt[1] = f2bf(p0.y); tt[2] = f2bf(p0.z); tt[3] = f2bf(p0.w);
                tt[4] = f2bf(p1.x); tt[5] = f2bf(p1.y); tt[6] = f2bf(p1.z); tt[7] = f2bf(p1.w);
                u.v = tt; FR[(4 + nt * 2 + kc) * 64 + lane] = u.f;
            }
        float4 f;
        f.x = bsh[m]; f.y = bsh[16 + m]; f.z = bsh[32 + m]; f.w = bsh[48 + m];
        FR[12 * 64 + lane] = f;
        f.x = dw1[m]; f.y = dw1[16 + m]; f.z = dw1[32 + m]; f.w = dw1[48 + m];
        FR[13 * 64 + lane] = f;
        f.x = XG[m]; f.y = XG[16 + m]; f.z = XG[32 + m]; f.w = XG[48 + m];
        FR[14 * 64 + lane] = f;
    }
}

// ---------------------------------------------------------------------------
// Kernel 3: k_main v5 — v1 structure (128-thr blocks, SEGW=2, 2-deep row
// prefetch) with a bf16 DOUBLE-BUFFERED tile: ONE lgkm fence per batch
// (batch n's reads are drained by batch n+1's fence before tile reuse at
// n+2) and direct s16x8 ds_read_b128 reads (no repack). LDS/block = 2 waves
// x 2 tiles x 2304 B = 9216 B ~= v1's 8704 B, so residency is preserved
// (the round-3/round-6 tests of these ideas were confounded with SEGW=4 /
// 4-wave blocks, which cut occupancy). Stored shorts = same truncation as
// the old pack_trunc read path -> bit-identical numerics.
// ---------------------------------------------------------------------------
#define LD2 72                  // shorts per tile row (144 B, 16B-aligned)
#define TILE2 (16 * LD2)        // shorts per tile (2304 B)
#define SEGW 2
__global__ void __launch_bounds__(128) k_main(const float* __restrict__ inp,
                                              const float* __restrict__ ws,
                                              const int* __restrict__ starts,
                                              float* __restrict__ out) {
    const int tid  = threadIdx.x;
    const int wv   = tid >> 6;
    const int lane = tid & 63;
    const int m = lane & 15;
    const int q = lane >> 4;
    const f32x4 zero = {0.f, 0.f, 0.f, 0.f};

    const float4* FR = (const float4*)(ws + FROFF);
    union { float4 f; s16x8 v; } u;
    s16x8 wfr[4];
#pragma unroll
    for (int nt = 0; nt < 4; ++nt) { u.f = FR[nt * 64 + lane]; wfr[nt] = u.v; }
    s16x8 bfr[4][2];
#pragma unroll
    for (int nt = 0; nt < 4; ++nt)
#pragma unroll
        for (int kc = 0; kc < 2; ++kc) { u.f = FR[(4 + nt * 2 + kc) * 64 + lane]; bfr[nt][kc] = u.v; }
    const float4 bb4  = FR[12 * 64 + lane];
    const float4 d14  = FR[13 * 64 + lane];
    const float4 xg4  = FR[14 * 64 + lane];
    const float bb[4]  = {bb4.x, bb4.y, bb4.z, bb4.w};
    const float d1v[4] = {d14.x, d14.y, d14.z, d14.w};
    const float xgv[4] = {xg4.x, xg4.y, xg4.z, xg4.w};

    __shared__ short sb16[2][2 * TILE2];     // [wave][double-buffered bf16 tile]
    short* const tbase = sb16[wv];

    const int w  = blockIdx.x * 2 + wv;    // 0..14999
    const int s0 = w * SEGW;

    int st1 = starts[s0 + 1];
    int st2 = (s0 + 2 < NSEG) ? starts[s0 + 2] : N_PTS;
    const int start   = starts[s0];
    const int end_all = st2;

    int cur = s0;
    int end_cur = st1;

    float sm[4]  = {0.f, 0.f, 0.f, 0.f};
    float mxv[4] = {-INFINITY, -INFINITY, -INFINITY, -INFINITY};

    auto flushseg = [&](int s) {
#pragma unroll
        for (int nt = 0; nt < 4; ++nt) {
            sm[nt] += __shfl_xor(sm[nt], 16, 64);
            sm[nt] += __shfl_xor(sm[nt], 32, 64);
            mxv[nt] = fmaxf(mxv[nt], __shfl_xor(mxv[nt], 16, 64));
            mxv[nt] = fmaxf(mxv[nt], __shfl_xor(mxv[nt], 32, 64));
        }
        float S = sm[0], M = mxv[0];
        if (q == 1) { S = sm[1]; M = mxv[1]; }
        if (q == 2) { S = sm[2]; M = mxv[2]; }
        if (q == 3) { S = sm[3]; M = mxv[3]; }
        out[(size_t)s * C + lane] = S + M;
#pragma unroll
        for (int nt = 0; nt < 4; ++nt) { sm[nt] = 0.f; mxv[nt] = -INFINITY; }
    };

    auto loadrows = [&](int pb) -> Rows {
        Rows R;
        R.r0 = R.r1 = R.r2 = R.r3 = make_float2(0.f, 0.f);
        const float* row = inp + (size_t)min(pb + m, N_PTS - 1) * CI;
        if (q == 0) {
            R.r0 = *(const float2*)(row);     R.r1 = *(const float2*)(row + 2);
            R.r2 = *(const float2*)(row + 4); R.r3 = *(const float2*)(row + 6);
        } else if (q == 1) {
            R.r0 = *(const float2*)(row + 8);
        }
        return R;
    };

    Rows A = loadrows(start);
    Rows B = (start + 16 < end_all) ? loadrows(start + 16) : A;

    int tog = 0;
    for (int base = start; base < end_all; base += 16, tog ^= 1) {
        short* const myt = tbase + tog * TILE2;
        Rows L = A;
        A = B;
        if (base + 32 < end_all) B = loadrows(base + 32);

        const int nb = min(16, end_all - base);

        // ---- A-frag of rows (K padded to 32, truncation pack)
        union { s16x8 v; unsigned uu[4]; } t;
        t.v = s16x8{0, 0, 0, 0, 0, 0, 0, 0};
        if (q < 2) t.uu[0] = pack_trunc(L.r0.x, L.r0.y);
        if (q == 0) {
            t.uu[1] = pack_trunc(L.r1.x, L.r1.y);
            t.uu[2] = pack_trunc(L.r2.x, L.r2.y);
            t.uu[3] = pack_trunc(L.r3.x, L.r3.y);
        }

        // ---- x' = rows @ W'^T  (C-layout: ch=16nt+m, pt=4q+r)
        f32x4 xt[4];
#pragma unroll
        for (int nt = 0; nt < 4; ++nt)
            xt[nt] = __builtin_amdgcn_mfma_f32_16x16x32_bf16(t.v, wfr[nt], zero, 0, 0, 0);

        // ---- BN + ReLU + swish; sw -> bf16 LDS tile [pt][ch] (truncate)
        float xn[4][4];
#pragma unroll
        for (int nt = 0; nt < 4; ++nt)
#pragma unroll
            for (int r = 0; r < 4; ++r) {
                float x = fmaxf(xt[nt][r] + bb[nt], 0.f);
                xn[nt][r] = x;
                float sg = x * d1v[nt];
                float sw = sg * frcp(1.f + __expf(-sg));
                myt[(4 * q + r) * LD2 + nt * 16 + m] =
                    (short)(__float_as_uint(sw) >> 16);
            }
        lds_fence();   // drains this tile's writes (RAW) and the OTHER tile's
                       // reads from last batch (WAR for batch n+2's overwrite)

        // ---- A-frags of sw: direct bf16x8 reads, lane(m,q) row pt=m
        s16x8 av[2];
#pragma unroll
        for (int kc = 0; kc < 2; ++kc)
            av[kc] = *(const s16x8*)(myt + m * LD2 + kc * 32 + q * 8);

        // ---- xl = sw @ pw1^T (C-layout, aligned with xn)
        f32x4 xi[4];
#pragma unroll
        for (int nt = 0; nt < 4; ++nt) {
            xi[nt] = __builtin_amdgcn_mfma_f32_16x16x32_bf16(av[0], bfr[nt][0], zero, 0, 0, 0);
            xi[nt] = __builtin_amdgcn_mfma_f32_16x16x32_bf16(av[1], bfr[nt][1], xi[nt], 0, 0, 0);
        }

#pragma unroll
        for (int nt = 0; nt < 4; ++nt)
#pragma unroll
            for (int r = 0; r < 4; ++r) {
                float v   = xi[nt][r] + xgv[nt];
                float wei = frcp(1.f + __expf(-v));
                float x   = xn[nt][r];
                xi[nt][r] = fmaf(x, wei, x);
            }

        // ---- segmented accumulate (<=1 boundary per batch: min seg len 33)
        const int fin = base + nb;
        if (fin <= end_cur) {
            if (nb == 16) {
#pragma unroll
                for (int nt = 0; nt < 4; ++nt)
#pragma unroll
                    for (int r = 0; r < 4; ++r) {
                        sm[nt] += xi[nt][r];
                        mxv[nt] = fmaxf(mxv[nt], xi[nt][r]);
                    }
            } else {
#pragma unroll
                for (int nt = 0; nt < 4; ++nt)
#pragma unroll
                    for (int r = 0; r < 4; ++r) {
                        bool act = (4 * q + r) < nb;
                        sm[nt] += act ? xi[nt][r] : 0.f;
                        mxv[nt] = fmaxf(mxv[nt], act ? xi[nt][r] : -INFINITY);
                    }
            }
            if (fin == end_cur) { flushseg(cur); ++cur; end_cur = st2; }
        } else {
            const int Bn = end_cur - base;   // 1..nb-1
#pragma unroll
            for (int nt = 0; nt < 4; ++nt)
#pragma unroll
                for (int r = 0; r < 4; ++r) {
                    bool act = (4 * q + r) < Bn;
                    sm[nt] += act ? xi[nt][r] : 0.f;
                    mxv[nt] = fmaxf(mxv[nt], act ? xi[nt][r] : -INFINITY);
                }
            flushseg(cur); ++cur;
#pragma unroll
            for (int nt = 0; nt < 4; ++nt)
#pragma unroll
                for (int r = 0; r < 4; ++r) {
                    int pt = 4 * q + r;
                    bool act = (pt >= Bn) && (pt < nb);
                    sm[nt] += act ? xi[nt][r] : 0.f;
                    mxv[nt] = fmaxf(mxv[nt], act ? xi[nt][r] : -INFINITY);
                }
            end_cur = st2;
        }
    }
}

extern "C" void kernel_launch(void* const* d_in, const int* in_sizes, int n_in,
                              void* d_out, int out_size, void* d_ws, size_t ws_size,
                              hipStream_t stream) {
    const float* inp   = (const float*)d_in[0];
    const int*   unq   = (const int*)d_in[1];
    const float* W     = (const float*)d_in[2];
    const float* gamma = (const float*)d_in[3];
    const float* beta  = (const float*)d_in[4];
    const float* dw1   = (const float*)d_in[5];
    const float* pw1   = (const float*)d_in[6];
    const float* dw2   = (const float*)d_in[7];
    const float* pw2   = (const float*)d_in[8];
    float* out = (float*)d_out;
    float* ws  = (float*)d_ws;
    int* starts = (int*)ws + 1024;

    hipMemsetAsync(ws, 0, 1024 * sizeof(float), stream);   // zero accumulators+ctr

    k_moments <<<1024, 256, 0, stream>>>(inp, unq, ws, starts);
    k_gstats  <<<1024, 256, 0, stream>>>(inp, W, gamma, beta, dw1, pw1, dw2, pw2, ws);
    k_main    <<<7500, 128, 0, stream>>>(inp, ws, starts, out);
}